// Round 6
// baseline (380.675 us; speedup 1.0000x reference)
//
#include <hip/hip_runtime.h>
#include <cstdint>

// ---------- helpers ----------
typedef __attribute__((ext_vector_type(8))) short short8;   // 8 x bf16 (4 VGPRs)
typedef __attribute__((ext_vector_type(4))) float f32x4;

__device__ __forceinline__ float b2f(unsigned short u) {
    return __uint_as_float(((unsigned int)u) << 16);
}
__device__ __forceinline__ unsigned short f2b(float f) {   // RNE f32->bf16
    unsigned int u = __float_as_uint(f);
    u += 0x7FFFu + ((u >> 16) & 1u);
    return (unsigned short)(u >> 16);
}

// ---------- fused transpose + fp32->bf16 convert for all 4 weights ----------
__global__ __launch_bounds__(256) void k_transpose_all(
        const float* __restrict__ w0, const float* __restrict__ w1,
        const float* __restrict__ w2, const float* __restrict__ w3,
        unsigned short* __restrict__ o0, unsigned short* __restrict__ o1,
        unsigned short* __restrict__ o2, unsigned short* __restrict__ o3) {
    __shared__ float tile[32][33];
    int b = blockIdx.x;
    const float* w; unsigned short* o; int K, N, nx, tb;
    if (b < 3072)      { w = w0; o = o0; K = 1024; N = 3072; nx = 96;  tb = b; }
    else if (b < 4096) { w = w1; o = o1; K = 1024; N = 1024; nx = 32;  tb = b - 3072; }
    else if (b < 8192) { w = w2; o = o2; K = 1024; N = 4096; nx = 128; tb = b - 4096; }
    else               { w = w3; o = o3; K = 4096; N = 1024; nx = 32;  tb = b - 8192; }
    int n0 = (tb % nx) * 32, k0 = (tb / nx) * 32;
    int tx = threadIdx.x, ty = threadIdx.y;
#pragma unroll
    for (int i = 0; i < 4; i++)
        tile[ty + 8 * i][tx] = w[(size_t)(k0 + ty + 8 * i) * N + n0 + tx];
    __syncthreads();
#pragma unroll
    for (int i = 0; i < 4; i++)
        o[(size_t)(n0 + ty + 8 * i) * K + k0 + tx] = f2b(tile[tx][ty + 8 * i]);
}

// ---------- layernorm (fp32 in, bf16 out), one row (C=1024) per block ----------
__global__ __launch_bounds__(256) void k_layernorm(
        const float* __restrict__ x, const float* __restrict__ w,
        unsigned short* __restrict__ out) {
    int row = blockIdx.x, tid = threadIdx.x;
    const float4* xr = (const float4*)(x + (size_t)row * 1024);
    float4 v = xr[tid];
    float s  = v.x + v.y + v.z + v.w;
    float ss = v.x * v.x + v.y * v.y + v.z * v.z + v.w * v.w;
#pragma unroll
    for (int off = 32; off >= 1; off >>= 1) {
        s  += __shfl_down(s, off);
        ss += __shfl_down(ss, off);
    }
    __shared__ float red[10];
    if ((tid & 63) == 0) { red[tid >> 6] = s; red[4 + (tid >> 6)] = ss; }
    __syncthreads();
    if (tid == 0) {
        float S  = red[0] + red[1] + red[2] + red[3];
        float SS = red[4] + red[5] + red[6] + red[7];
        float mu  = S * (1.0f / 1024.0f);
        float var = SS * (1.0f / 1024.0f) - mu * mu;
        red[8] = mu; red[9] = rsqrtf(var + 1e-5f);
    }
    __syncthreads();
    float mu = red[8], rs = red[9];
    float4 wv = ((const float4*)w)[tid];
    ushort4 pk;
    pk.x = f2b((v.x - mu) * rs * wv.x);
    pk.y = f2b((v.y - mu) * rs * wv.y);
    pk.z = f2b((v.z - mu) * rs * wv.z);
    pk.w = f2b((v.w - mu) * rs * wv.w);
    *(ushort4*)(out + (size_t)row * 1024 + tid * 4) = pk;
}

// ---------- fused split-K reduce + layernorm: x2 = res+p0+p1; h = LN(x2)*w ----
__global__ __launch_bounds__(256) void k_reduce_ln(
        const float* __restrict__ res, const float* __restrict__ p0,
        const float* __restrict__ p1, const float* __restrict__ w,
        float* __restrict__ xout, unsigned short* __restrict__ hout) {
    int row = blockIdx.x, tid = threadIdx.x;
    size_t i = (size_t)row * 256 + tid;
    float4 a = ((const float4*)res)[i];
    float4 b = ((const float4*)p0)[i];
    float4 c = ((const float4*)p1)[i];
    float4 v;
    v.x = a.x + b.x + c.x; v.y = a.y + b.y + c.y;
    v.z = a.z + b.z + c.z; v.w = a.w + b.w + c.w;
    ((float4*)xout)[i] = v;
    float s  = v.x + v.y + v.z + v.w;
    float ss = v.x * v.x + v.y * v.y + v.z * v.z + v.w * v.w;
#pragma unroll
    for (int off = 32; off >= 1; off >>= 1) {
        s  += __shfl_down(s, off);
        ss += __shfl_down(ss, off);
    }
    __shared__ float red[10];
    if ((tid & 63) == 0) { red[tid >> 6] = s; red[4 + (tid >> 6)] = ss; }
    __syncthreads();
    if (tid == 0) {
        float S  = red[0] + red[1] + red[2] + red[3];
        float SS = red[4] + red[5] + red[6] + red[7];
        float mu  = S * (1.0f / 1024.0f);
        float var = SS * (1.0f / 1024.0f) - mu * mu;
        red[8] = mu; red[9] = rsqrtf(var + 1e-5f);
    }
    __syncthreads();
    float mu = red[8], rs = red[9];
    float4 wv = ((const float4*)w)[tid];
    ushort4 pk;
    pk.x = f2b((v.x - mu) * rs * wv.x);
    pk.y = f2b((v.y - mu) * rs * wv.y);
    pk.z = f2b((v.z - mu) * rs * wv.z);
    pk.w = f2b((v.w - mu) * rs * wv.w);
    *(ushort4*)(hout + (size_t)row * 1024 + tid * 4) = pk;
}

// ---------- split-K reduce: out = res + p0 + p1 (fp32, vectorized) ----------
__global__ __launch_bounds__(256) void k_reduce(
        const float* __restrict__ res, const float* __restrict__ p0,
        const float* __restrict__ p1, float* __restrict__ out, int n4) {
    int i = blockIdx.x * 256 + threadIdx.x;
    if (i < n4) {
        float4 a = ((const float4*)res)[i];
        float4 b = ((const float4*)p0)[i];
        float4 c = ((const float4*)p1)[i];
        a.x += b.x + c.x; a.y += b.y + c.y; a.z += b.z + c.z; a.w += b.w + c.w;
        ((float4*)out)[i] = a;
    }
}

// ---------- bf16 MFMA GEMM: C[M][N] = A[M][K] @ BT[N][K]^T (+ epilogue) ----------
// R0-exact: BK=64, column-rotate LDS swizzle, named-scalar VGPR prefetch.
// TM=128/TN=128: 2x2 waves of 64x64. Split-K via gridDim.z (EPI=0 partials).
// EPI: 0 = f32 partial store (z-offset), 1 = bf16, 3 = gelu -> bf16
template <int EPI, int TM, int TN, int MINW>
__global__ __launch_bounds__(256, MINW) void k_gemm_bt(
        const unsigned short* __restrict__ A, const unsigned short* __restrict__ BT,
        const float* __restrict__ RES, void* __restrict__ OUT,
        int M, int N, int K) {
    constexpr int WT = (TM == 128) ? 64 : 32;      // wave tile (square)
    constexpr int MI = WT / 16;                    // subtiles per wave (each dim)
    constexpr int NA = TM / 32, NB = TN / 32;      // staging uint4-chunks per thread
    __shared__ __align__(16) unsigned short As[TM * 64];
    __shared__ __align__(16) unsigned short Bs[TN * 64];
    int tid  = threadIdx.x;
    int lane = tid & 63, wave = tid >> 6;
    int quad = lane >> 4, qr = lane & 15;
    int wm_off = (wave >> 1) * WT;
    int wn_off = (wave & 1) * WT;
    int m0 = blockIdx.y * TM, n0 = blockIdx.x * TN;
    int ks = K / gridDim.z;                         // split-K slice
    int kbeg = blockIdx.z * ks;
    int r0 = tid >> 3;                      // 0..31
    int c0 = (tid & 7) * 8;
    int cs = 8 * (((tid & 7) + (r0 & 7)) & 7);
    int cswz[2];
#pragma unroll
    for (int kk = 0; kk < 2; kk++) cswz[kk] = 8 * (((kk * 4) + quad + (qr & 7)) & 7);

    const unsigned short* Ap = A  + (size_t)(m0 + r0) * K + kbeg + c0;
    const unsigned short* Bp = BT + (size_t)(n0 + r0) * K + kbeg + c0;
    const size_t sA = (size_t)32 * K;

    uint4 pa0, pa1, pa2, pa3, pb0, pb1, pb2, pb3;
    pa0 = *(const uint4*)(Ap);
    pa1 = *(const uint4*)(Ap + sA);
    if constexpr (NA == 4) {
        pa2 = *(const uint4*)(Ap + 2 * sA);
        pa3 = *(const uint4*)(Ap + 3 * sA);
    }
    pb0 = *(const uint4*)(Bp);
    pb1 = *(const uint4*)(Bp + sA);
    if constexpr (NB == 4) {
        pb2 = *(const uint4*)(Bp + 2 * sA);
        pb3 = *(const uint4*)(Bp + 3 * sA);
    }

    f32x4 acc[MI][MI] = {};
    for (int k0 = 0; k0 < ks; k0 += 64) {
        __syncthreads();   // prev compute's LDS reads done
        *(uint4*)&As[(r0)      * 64 + cs] = pa0;
        *(uint4*)&As[(32 + r0) * 64 + cs] = pa1;
        if constexpr (NA == 4) {
            *(uint4*)&As[(64 + r0) * 64 + cs] = pa2;
            *(uint4*)&As[(96 + r0) * 64 + cs] = pa3;
        }
        *(uint4*)&Bs[(r0)      * 64 + cs] = pb0;
        *(uint4*)&Bs[(32 + r0) * 64 + cs] = pb1;
        if constexpr (NB == 4) {
            *(uint4*)&Bs[(64 + r0) * 64 + cs] = pb2;
            *(uint4*)&Bs[(96 + r0) * 64 + cs] = pb3;
        }
        __syncthreads();
        if (k0 + 64 < ks) {   // prefetch next slab; vmcnt waits land next iteration
            int k = k0 + 64;
            pa0 = *(const uint4*)(Ap + k);
            pa1 = *(const uint4*)(Ap + sA + k);
            if constexpr (NA == 4) {
                pa2 = *(const uint4*)(Ap + 2 * sA + k);
                pa3 = *(const uint4*)(Ap + 3 * sA + k);
            }
            pb0 = *(const uint4*)(Bp + k);
            pb1 = *(const uint4*)(Bp + sA + k);
            if constexpr (NB == 4) {
                pb2 = *(const uint4*)(Bp + 2 * sA + k);
                pb3 = *(const uint4*)(Bp + 3 * sA + k);
            }
        }
#pragma unroll
        for (int kk = 0; kk < 2; kk++) {
            short8 af[MI], bfr[MI];
#pragma unroll
            for (int i = 0; i < MI; i++) af[i]  = *(const short8*)&As[(wm_off + i * 16 + qr) * 64 + cswz[kk]];
#pragma unroll
            for (int j = 0; j < MI; j++) bfr[j] = *(const short8*)&Bs[(wn_off + j * 16 + qr) * 64 + cswz[kk]];
#pragma unroll
            for (int i = 0; i < MI; i++)
#pragma unroll
                for (int j = 0; j < MI; j++)
                    acc[i][j] = __builtin_amdgcn_mfma_f32_16x16x32_bf16(af[i], bfr[j], acc[i][j], 0, 0, 0);
        }
    }
    // epilogue: C/D layout col=lane&15, row=quad*4+reg
    float* outz = (EPI == 0) ? ((float*)OUT + (size_t)blockIdx.z * M * N) : (float*)OUT;
#pragma unroll
    for (int i = 0; i < MI; i++) {
#pragma unroll
        for (int j = 0; j < MI; j++) {
#pragma unroll
            for (int r = 0; r < 4; r++) {
                int row = m0 + wm_off + i * 16 + quad * 4 + r;
                int col = n0 + wn_off + j * 16 + qr;
                size_t idx = (size_t)row * N + col;
                float v = acc[i][j][r];
                if (EPI == 0)      outz[idx] = v;
                else if (EPI == 1) ((unsigned short*)OUT)[idx] = f2b(v);
                else if (EPI == 2) ((float*)OUT)[idx] = RES[idx] + v;
                else {
                    // tanh-form GELU via exp2: g = v*t/(t+1), t = 2^(2u/ln2)
                    float u = v * fmaf(v * v, 0.035677408f, 0.79788456f);
                    float e = fminf(u * 2.885390082f, 80.0f);   // guard inf/inf
                    float t = exp2f(e);
                    float g = v * t / (t + 1.0f);
                    ((unsigned short*)OUT)[idx] = f2b(g);
                }
            }
        }
    }
}

// ---------- MFMA causal flash attention, K-chunk=128, static-max softmax ------
// R0 kernel internals (proven 98us) with R6 work-splitting: attn was shown to
// be CONCURRENCY-limited (1024 blocks of 1..33 iters; occupancy 29% with no
// resource limit binding). qb>=32 blocks are split into two key-range segments
// (every block <=17 iters, 1536 blocks, near-LPT dispatch). Static-max softmax
// makes partials trivially additive: combine = add O, add l, divide (no
// rescale). Split blocks write f32 partials; k_attn_combine sums+normalizes.
__global__ __launch_bounds__(256) void k_attn(
        const unsigned short* __restrict__ qkv, unsigned short* __restrict__ out,
        float* __restrict__ pO, float* __restrict__ pL) {
    __shared__ unsigned short Ks[128][72];      // K rows (Q staged here first)
    __shared__ unsigned short Vt[64][136];      // [dim][key 0..127]
    __shared__ unsigned short Ps[4][16][136];   // per wave [q][key 0..127] (wave-private)

    const float C1 = 0.18033688f;   // 0.125 * log2(e)
    const float C2 = 5.77078016f;   // 4.0   * log2(e)  (static max m=4)

    // block -> (h, qb, segment): per head, 96 units in ~length-descending order
    //  r=0..3: split halves of qb=63-2k / 62-2k (seg1 = diagonal half first)
    //  r=4..5: unsplit qb=31-2k / 30-2k
    int l = blockIdx.x;
    int h = l & 15;
    int u = l >> 4;                    // 0..95
    int k_ = u / 6, r_ = u - 6 * k_;
    int qb, seg, split;
    if (r_ < 4)      { qb = (r_ < 2 ? 63 : 62) - 2 * k_; seg = 1 - (r_ & 1); split = 1; }
    else             { qb = (r_ == 4 ? 31 : 30) - 2 * k_; seg = 0; split = 0; }
    int q0 = qb * 64;
    int nc = (qb >> 1) + 1;            // total 128-key iterations for this qb
    int kcbeg = (split && seg == 1) ? 2 * (nc >> 1) : 0;
    int kcend = (split && seg == 0) ? 2 * (nc >> 1) : 2 * nc;

    int tid = threadIdx.x;
    int wave = tid >> 6, lane = tid & 63;
    int lane16 = lane & 15, quad = lane >> 4;

    // ---- stage Q through Ks rows 0..63, read loop-invariant A-frags ----
    {
        int srow = tid >> 2, sc0 = (tid & 3) * 16;
        size_t base = (size_t)(q0 + srow) * 3072 + h * 64 + sc0;
        *(uint4*)&Ks[srow][sc0]     = *(const uint4*)&qkv[base];
        *(uint4*)&Ks[srow][sc0 + 8] = *(const uint4*)&qkv[base + 8];
    }
    __syncthreads();
    short8 aq0 = *(const short8*)&Ks[wave * 16 + lane16][quad * 8];
    short8 aq1 = *(const short8*)&Ks[wave * 16 + lane16][32 + quad * 8];

    f32x4 Oacc[4] = {};                // lane holds O[q=quad*4+r][d=dt*16+lane16]
    float l_part[4] = {0.f, 0.f, 0.f, 0.f};

    int srow = tid >> 1, sc0 = (tid & 1) * 32;   // K staging coords
    int vk = (lane & 31) * 2;                    // V staging: even local key
    int d0 = wave * 16 + (lane >> 5) * 8;

    // prefetch registers (chunk kc): K 4x uint4, V 4x uint4
    uint4 pk0, pk1, pk2, pk3, pv0, pv1, pv2, pv3;
    {   // prefetch first chunk of this segment
        size_t base = (size_t)(kcbeg * 64 + srow) * 3072 + 1024 + h * 64 + sc0;
        pk0 = *(const uint4*)&qkv[base];
        pk1 = *(const uint4*)&qkv[base + 8];
        pk2 = *(const uint4*)&qkv[base + 16];
        pk3 = *(const uint4*)&qkv[base + 24];
        size_t vb0 = (size_t)(kcbeg * 64 + vk) * 3072 + 2048 + h * 64 + d0;
        pv0 = *(const uint4*)&qkv[vb0];
        pv1 = *(const uint4*)&qkv[vb0 + 3072];
        size_t vb1 = (size_t)(kcbeg * 64 + 64 + vk) * 3072 + 2048 + h * 64 + d0;
        pv2 = *(const uint4*)&qkv[vb1];
        pv3 = *(const uint4*)&qkv[vb1 + 3072];
    }

    for (int kc = kcbeg; kc < kcend; kc += 2) {   // 128 keys per iteration
        __syncthreads();   // prev-iter LDS reads done (covers Q-frag reads at first)
        {   // write prefetched K chunk to LDS
            *(uint4*)&Ks[srow][sc0]      = pk0;
            *(uint4*)&Ks[srow][sc0 + 8]  = pk1;
            *(uint4*)&Ks[srow][sc0 + 16] = pk2;
            *(uint4*)&Ks[srow][sc0 + 24] = pk3;
        }
        {   // write prefetched V chunk TRANSPOSED, key-pairs packed as b32
            const unsigned short* pe0 = (const unsigned short*)&pv0;
            const unsigned short* po0 = (const unsigned short*)&pv1;
            const unsigned short* pe1 = (const unsigned short*)&pv2;
            const unsigned short* po1 = (const unsigned short*)&pv3;
#pragma unroll
            for (int j = 0; j < 8; j++) {
                *(uint32_t*)&Vt[d0 + j][vk]      = (uint32_t)pe0[j] | ((uint32_t)po0[j] << 16);
                *(uint32_t*)&Vt[d0 + j][64 + vk] = (uint32_t)pe1[j] | ((uint32_t)po1[j] << 16);
            }
        }
        __syncthreads();

        if (kc + 2 < kcend) {   // issue next chunk's loads; overlap with compute below
            size_t base = (size_t)((kc + 2) * 64 + srow) * 3072 + 1024 + h * 64 + sc0;
            pk0 = *(const uint4*)&qkv[base];
            pk1 = *(const uint4*)&qkv[base + 8];
            pk2 = *(const uint4*)&qkv[base + 16];
            pk3 = *(const uint4*)&qkv[base + 24];
            size_t vb0 = (size_t)((kc + 2) * 64 + vk) * 3072 + 2048 + h * 64 + d0;
            pv0 = *(const uint4*)&qkv[vb0];
            pv1 = *(const uint4*)&qkv[vb0 + 3072];
            size_t vb1 = (size_t)((kc + 3) * 64 + vk) * 3072 + 2048 + h * 64 + d0;
            pv2 = *(const uint4*)&qkv[vb1];
            pv3 = *(const uint4*)&qkv[vb1 + 3072];
        }

        // ---- S = Q K^T  (16q x 128k per wave) ----
        f32x4 sacc[8] = {};
#pragma unroll
        for (int kt = 0; kt < 8; kt++) {
            short8 bk0 = *(const short8*)&Ks[kt * 16 + lane16][quad * 8];
            short8 bk1 = *(const short8*)&Ks[kt * 16 + lane16][32 + quad * 8];
            sacc[kt] = __builtin_amdgcn_mfma_f32_16x16x32_bf16(aq0, bk0, sacc[kt], 0, 0, 0);
            sacc[kt] = __builtin_amdgcn_mfma_f32_16x16x32_bf16(aq1, bk1, sacc[kt], 0, 0, 0);
        }

        // ---- static-max softmax: p = 2^(s*C1 - C2); mask only on diag chunk ----
        bool domask = (kc + 2 > qb);   // wave-uniform; only last chunk of seg1/unsplit
#pragma unroll
        for (int r = 0; r < 4; r++) {
            int qrow = q0 + wave * 16 + quad * 4 + r;
#pragma unroll
            for (int kt = 0; kt < 8; kt++) {
                float s = sacc[kt][r];
                if (domask) {
                    int key = kc * 64 + kt * 16 + lane16;
                    s = (key <= qrow) ? s : -__builtin_inff();
                }
                float p = exp2f(fmaf(s, C1, -C2));   // masked -> 0
                l_part[r] += p;
                Ps[wave][quad * 4 + r][kt * 16 + lane16] =
                    (unsigned short)(__float_as_uint(p) >> 16);   // truncated bf16
            }
        }
        // no barrier: Ps is wave-private; in-wave RAW ordered by lgkmcnt

        // ---- O += P V  (A=P rows, B=V^T rows, both key-contiguous) ----
#pragma unroll
        for (int s = 0; s < 4; s++) {
            short8 ap = *(const short8*)&Ps[wave][lane16][s * 32 + quad * 8];
#pragma unroll
            for (int dt = 0; dt < 4; dt++) {
                short8 bv = *(const short8*)&Vt[dt * 16 + lane16][s * 32 + quad * 8];
                Oacc[dt] = __builtin_amdgcn_mfma_f32_16x16x32_bf16(ap, bv, Oacc[dt], 0, 0, 0);
            }
        }
    }

    // l reduction (sum over lane16 key-group)
    float lfull[4];
#pragma unroll
    for (int r = 0; r < 4; r++) {
        float lf = l_part[r];
        lf += __shfl_xor(lf, 1);
        lf += __shfl_xor(lf, 2);
        lf += __shfl_xor(lf, 4);
        lf += __shfl_xor(lf, 8);
        lfull[r] = lf;
    }

    if (!split) {   // final output (divide) - identical to R0
#pragma unroll
        for (int dt = 0; dt < 4; dt++) {
#pragma unroll
            for (int r = 0; r < 4; r++) {
                int qrow = q0 + wave * 16 + quad * 4 + r;
                out[(size_t)qrow * 1024 + h * 64 + dt * 16 + lane16] =
                    f2b(Oacc[dt][r] * (1.0f / lfull[r]));
            }
        }
    } else {        // f32 partials: O and l (additive thanks to static max)
        size_t pb = ((((size_t)seg * 16 + h) * 32 + (qb - 32)) * 64) * 64;
#pragma unroll
        for (int dt = 0; dt < 4; dt++) {
#pragma unroll
            for (int r = 0; r < 4; r++) {
                int q = wave * 16 + quad * 4 + r;
                pO[pb + (size_t)q * 64 + dt * 16 + lane16] = Oacc[dt][r];
            }
        }
        if (lane16 == 0) {
            size_t lb = (((size_t)seg * 16 + h) * 32 + (qb - 32)) * 64;
#pragma unroll
            for (int r = 0; r < 4; r++)
                pL[lb + wave * 16 + quad * 4 + r] = lfull[r];
        }
    }
}

// ---------- combine split-attn partials: out = (O0+O1)/(l0+l1) -> bf16 -------
__global__ __launch_bounds__(256) void k_attn_combine(
        const float* __restrict__ pO, const float* __restrict__ pL,
        unsigned short* __restrict__ out) {
    int b = blockIdx.x;            // 512 blocks: (h, qb-32)
    int h = b & 15, qi = b >> 4;   // qi = qb-32 in 0..31
    int q0 = (32 + qi) * 64;
    int t = threadIdx.x;
    int q = t >> 2, dd = (t & 3) * 16;
    size_t b0 = ((((size_t)0 * 16 + h) * 32 + qi) * 64 + q) * 64 + dd;
    size_t b1 = ((((size_t)1 * 16 + h) * 32 + qi) * 64 + q) * 64 + dd;
    float l0 = pL[(((size_t)0 * 16 + h) * 32 + qi) * 64 + q];
    float l1 = pL[(((size_t)1 * 16 + h) * 32 + qi) * 64 + q];
    float inv = 1.0f / (l0 + l1);
    unsigned short* op = out + (size_t)(q0 + q) * 1024 + h * 64 + dd;
#pragma unroll
    for (int j = 0; j < 4; j++) {
        float4 a = ((const float4*)(pO + b0))[j];
        float4 c = ((const float4*)(pO + b1))[j];
        ushort4 pk;
        pk.x = f2b((a.x + c.x) * inv);
        pk.y = f2b((a.y + c.y) * inv);
        pk.z = f2b((a.z + c.z) * inv);
        pk.w = f2b((a.w + c.w) * inv);
        *(ushort4*)(op + j * 4) = pk;
    }
}

// ---------- launch ----------
extern "C" void kernel_launch(void* const* d_in, const int* in_sizes, int n_in,
                              void* d_out, int out_size, void* d_ws, size_t ws_size,
                              hipStream_t stream) {
    const float* x      = (const float*)d_in[0];
    const float* w_qkv  = (const float*)d_in[1];
    const float* w_attn = (const float*)d_in[2];
    const float* w_fc   = (const float*)d_in[3];
    const float* w_mlp  = (const float*)d_in[4];
    const float* ln1w   = (const float*)d_in[5];
    const float* ln2w   = (const float*)d_in[6];

    char* ws = (char*)d_ws;   // total 116 MB (region reuse for split-K partials)
    unsigned short* h      = (unsigned short*)(ws + 0);          //  8 MB
    unsigned short* wqkvT  = (unsigned short*)(ws + 8388608);    //  6 MB
    unsigned short* wattnT = (unsigned short*)(ws + 14680064);   //  2 MB
    unsigned short* wfcT   = (unsigned short*)(ws + 16777216);   //  8 MB
    unsigned short* wmlpT  = (unsigned short*)(ws + 25165824);   //  8 MB
    unsigned short* qkv    = (unsigned short*)(ws + 33554432);   // 24 MB
    unsigned short* attno  = (unsigned short*)(ws + 58720256);   //  8 MB
    float*          x2     = (float*)(ws + 67108864);            // 16 MB
    unsigned short* fcact  = (unsigned short*)(ws + 83886080);   // 32 MB
    // attn split partials (region-reuse of fcact, dead until fc GEMM):
    float* pO = (float*)(ws + 83886080);    // 16.8 MB
    float* pL = (float*)(ws + 100663296);   // 256 KB
    // split-K partials (32 MB each, region-reuse of dead buffers):
    float* pA = (float*)(ws + 83886080);   // attn_proj partials: fcact region
    float* pM = (float*)(ws + 33554432);   // mlp partials: qkv+attno region
    float* outF = (float*)d_out;

    k_transpose_all<<<12288, dim3(32, 8), 0, stream>>>(
        w_qkv, w_attn, w_fc, w_mlp, wqkvT, wattnT, wfcT, wmlpT);

    k_layernorm<<<4096, 256, 0, stream>>>(x, ln1w, h);
    k_gemm_bt<1, 128, 128, 3><<<dim3(24, 32), 256, 0, stream>>>(h, wqkvT, nullptr, qkv, 4096, 3072, 1024);
    k_attn<<<1536, 256, 0, stream>>>(qkv, attno, pO, pL);
    k_attn_combine<<<512, 256, 0, stream>>>(pO, pL, attno);
    // attn_proj: split-K=2, fp32 partials -> pA; fused reduce+LN adds residual x
    k_gemm_bt<0, 128, 128, 3><<<dim3(8, 32, 2), 256, 0, stream>>>(attno, wattnT, nullptr, pA, 4096, 1024, 1024);
    k_reduce_ln<<<4096, 256, 0, stream>>>(x, pA, pA + 4194304, ln2w, x2, h);
    k_gemm_bt<3, 128, 128, 3><<<dim3(32, 32), 256, 0, stream>>>(h, wfcT, nullptr, fcact, 4096, 4096, 1024);
    // mlp_proj: split-K=2, fp32 partials -> pM; reduce adds residual x2
    k_gemm_bt<0, 128, 128, 3><<<dim3(8, 32, 2), 256, 0, stream>>>(fcact, wmlpT, nullptr, pM, 4096, 1024, 4096);
    k_reduce<<<4096, 256, 0, stream>>>(x2, pM, pM + 4194304, outF, 1048576);
}

// Round 7
// 364.146 us; speedup vs baseline: 1.0454x; 1.0454x over previous
//
#include <hip/hip_runtime.h>
#include <cstdint>

// ---------- helpers ----------
typedef __attribute__((ext_vector_type(8))) short short8;   // 8 x bf16 (4 VGPRs)
typedef __attribute__((ext_vector_type(4))) float f32x4;

__device__ __forceinline__ float b2f(unsigned short u) {
    return __uint_as_float(((unsigned int)u) << 16);
}
__device__ __forceinline__ unsigned short f2b(float f) {   // RNE f32->bf16
    unsigned int u = __float_as_uint(f);
    u += 0x7FFFu + ((u >> 16) & 1u);
    return (unsigned short)(u >> 16);
}
// async global->LDS, 16B per lane; lds dest = wave-uniform base + lane*16B
__device__ __forceinline__ void gload16(const unsigned short* g, unsigned short* l) {
    __builtin_amdgcn_global_load_lds(
        (const __attribute__((address_space(1))) void*)g,
        (__attribute__((address_space(3))) void*)l, 16, 0, 0);
}

// ---------- fused transpose + fp32->bf16 convert for all 4 weights ----------
__global__ __launch_bounds__(256) void k_transpose_all(
        const float* __restrict__ w0, const float* __restrict__ w1,
        const float* __restrict__ w2, const float* __restrict__ w3,
        unsigned short* __restrict__ o0, unsigned short* __restrict__ o1,
        unsigned short* __restrict__ o2, unsigned short* __restrict__ o3) {
    __shared__ float tile[32][33];
    int b = blockIdx.x;
    const float* w; unsigned short* o; int K, N, nx, tb;
    if (b < 3072)      { w = w0; o = o0; K = 1024; N = 3072; nx = 96;  tb = b; }
    else if (b < 4096) { w = w1; o = o1; K = 1024; N = 1024; nx = 32;  tb = b - 3072; }
    else if (b < 8192) { w = w2; o = o2; K = 1024; N = 4096; nx = 128; tb = b - 4096; }
    else               { w = w3; o = o3; K = 4096; N = 1024; nx = 32;  tb = b - 8192; }
    int n0 = (tb % nx) * 32, k0 = (tb / nx) * 32;
    int tx = threadIdx.x, ty = threadIdx.y;
#pragma unroll
    for (int i = 0; i < 4; i++)
        tile[ty + 8 * i][tx] = w[(size_t)(k0 + ty + 8 * i) * N + n0 + tx];
    __syncthreads();
#pragma unroll
    for (int i = 0; i < 4; i++)
        o[(size_t)(n0 + ty + 8 * i) * K + k0 + tx] = f2b(tile[tx][ty + 8 * i]);
}

// ---------- layernorm (fp32 in, bf16 out), one row (C=1024) per block ----------
__global__ __launch_bounds__(256) void k_layernorm(
        const float* __restrict__ x, const float* __restrict__ w,
        unsigned short* __restrict__ out) {
    int row = blockIdx.x, tid = threadIdx.x;
    const float4* xr = (const float4*)(x + (size_t)row * 1024);
    float4 v = xr[tid];
    float s  = v.x + v.y + v.z + v.w;
    float ss = v.x * v.x + v.y * v.y + v.z * v.z + v.w * v.w;
#pragma unroll
    for (int off = 32; off >= 1; off >>= 1) {
        s  += __shfl_down(s, off);
        ss += __shfl_down(ss, off);
    }
    __shared__ float red[10];
    if ((tid & 63) == 0) { red[tid >> 6] = s; red[4 + (tid >> 6)] = ss; }
    __syncthreads();
    if (tid == 0) {
        float S  = red[0] + red[1] + red[2] + red[3];
        float SS = red[4] + red[5] + red[6] + red[7];
        float mu  = S * (1.0f / 1024.0f);
        float var = SS * (1.0f / 1024.0f) - mu * mu;
        red[8] = mu; red[9] = rsqrtf(var + 1e-5f);
    }
    __syncthreads();
    float mu = red[8], rs = red[9];
    float4 wv = ((const float4*)w)[tid];
    ushort4 pk;
    pk.x = f2b((v.x - mu) * rs * wv.x);
    pk.y = f2b((v.y - mu) * rs * wv.y);
    pk.z = f2b((v.z - mu) * rs * wv.z);
    pk.w = f2b((v.w - mu) * rs * wv.w);
    *(ushort4*)(out + (size_t)row * 1024 + tid * 4) = pk;
}

// ---------- fused split-K reduce + layernorm: x2 = res+p0+p1; h = LN(x2)*w ----
__global__ __launch_bounds__(256) void k_reduce_ln(
        const float* __restrict__ res, const float* __restrict__ p0,
        const float* __restrict__ p1, const float* __restrict__ w,
        float* __restrict__ xout, unsigned short* __restrict__ hout) {
    int row = blockIdx.x, tid = threadIdx.x;
    size_t i = (size_t)row * 256 + tid;
    float4 a = ((const float4*)res)[i];
    float4 b = ((const float4*)p0)[i];
    float4 c = ((const float4*)p1)[i];
    float4 v;
    v.x = a.x + b.x + c.x; v.y = a.y + b.y + c.y;
    v.z = a.z + b.z + c.z; v.w = a.w + b.w + c.w;
    ((float4*)xout)[i] = v;
    float s  = v.x + v.y + v.z + v.w;
    float ss = v.x * v.x + v.y * v.y + v.z * v.z + v.w * v.w;
#pragma unroll
    for (int off = 32; off >= 1; off >>= 1) {
        s  += __shfl_down(s, off);
        ss += __shfl_down(ss, off);
    }
    __shared__ float red[10];
    if ((tid & 63) == 0) { red[tid >> 6] = s; red[4 + (tid >> 6)] = ss; }
    __syncthreads();
    if (tid == 0) {
        float S  = red[0] + red[1] + red[2] + red[3];
        float SS = red[4] + red[5] + red[6] + red[7];
        float mu  = S * (1.0f / 1024.0f);
        float var = SS * (1.0f / 1024.0f) - mu * mu;
        red[8] = mu; red[9] = rsqrtf(var + 1e-5f);
    }
    __syncthreads();
    float mu = red[8], rs = red[9];
    float4 wv = ((const float4*)w)[tid];
    ushort4 pk;
    pk.x = f2b((v.x - mu) * rs * wv.x);
    pk.y = f2b((v.y - mu) * rs * wv.y);
    pk.z = f2b((v.z - mu) * rs * wv.z);
    pk.w = f2b((v.w - mu) * rs * wv.w);
    *(ushort4*)(hout + (size_t)row * 1024 + tid * 4) = pk;
}

// ---------- split-K reduce: out = res + p0 + p1 (fp32, vectorized) ----------
__global__ __launch_bounds__(256) void k_reduce(
        const float* __restrict__ res, const float* __restrict__ p0,
        const float* __restrict__ p1, float* __restrict__ out, int n4) {
    int i = blockIdx.x * 256 + threadIdx.x;
    if (i < n4) {
        float4 a = ((const float4*)res)[i];
        float4 b = ((const float4*)p0)[i];
        float4 c = ((const float4*)p1)[i];
        a.x += b.x + c.x; a.y += b.y + c.y; a.z += b.z + c.z; a.w += b.w + c.w;
        ((float4*)out)[i] = a;
    }
}

// ---------- bf16 MFMA GEMM (128^2, 2-barrier, reg-staged) — R0-exact ----------
// Used for the skinny N=1024 split-K GEMMs.
// EPI: 0 = f32 partial store (z-offset), 1 = bf16, 3 = gelu -> bf16
template <int EPI, int TM, int TN, int MINW>
__global__ __launch_bounds__(256, MINW) void k_gemm_bt(
        const unsigned short* __restrict__ A, const unsigned short* __restrict__ BT,
        const float* __restrict__ RES, void* __restrict__ OUT,
        int M, int N, int K) {
    constexpr int WT = (TM == 128) ? 64 : 32;      // wave tile (square)
    constexpr int MI = WT / 16;                    // subtiles per wave (each dim)
    constexpr int NA = TM / 32, NB = TN / 32;      // staging uint4-chunks per thread
    __shared__ __align__(16) unsigned short As[TM * 64];
    __shared__ __align__(16) unsigned short Bs[TN * 64];
    int tid  = threadIdx.x;
    int lane = tid & 63, wave = tid >> 6;
    int quad = lane >> 4, qr = lane & 15;
    int wm_off = (wave >> 1) * WT;
    int wn_off = (wave & 1) * WT;
    int m0 = blockIdx.y * TM, n0 = blockIdx.x * TN;
    int ks = K / gridDim.z;                         // split-K slice
    int kbeg = blockIdx.z * ks;
    int r0 = tid >> 3;                      // 0..31
    int c0 = (tid & 7) * 8;
    int cs = 8 * (((tid & 7) + (r0 & 7)) & 7);
    int cswz[2];
#pragma unroll
    for (int kk = 0; kk < 2; kk++) cswz[kk] = 8 * (((kk * 4) + quad + (qr & 7)) & 7);

    const unsigned short* Ap = A  + (size_t)(m0 + r0) * K + kbeg + c0;
    const unsigned short* Bp = BT + (size_t)(n0 + r0) * K + kbeg + c0;
    const size_t sA = (size_t)32 * K;

    uint4 pa0, pa1, pa2, pa3, pb0, pb1, pb2, pb3;
    pa0 = *(const uint4*)(Ap);
    pa1 = *(const uint4*)(Ap + sA);
    if constexpr (NA == 4) {
        pa2 = *(const uint4*)(Ap + 2 * sA);
        pa3 = *(const uint4*)(Ap + 3 * sA);
    }
    pb0 = *(const uint4*)(Bp);
    pb1 = *(const uint4*)(Bp + sA);
    if constexpr (NB == 4) {
        pb2 = *(const uint4*)(Bp + 2 * sA);
        pb3 = *(const uint4*)(Bp + 3 * sA);
    }

    f32x4 acc[MI][MI] = {};
    for (int k0 = 0; k0 < ks; k0 += 64) {
        __syncthreads();   // prev compute's LDS reads done
        *(uint4*)&As[(r0)      * 64 + cs] = pa0;
        *(uint4*)&As[(32 + r0) * 64 + cs] = pa1;
        if constexpr (NA == 4) {
            *(uint4*)&As[(64 + r0) * 64 + cs] = pa2;
            *(uint4*)&As[(96 + r0) * 64 + cs] = pa3;
        }
        *(uint4*)&Bs[(r0)      * 64 + cs] = pb0;
        *(uint4*)&Bs[(32 + r0) * 64 + cs] = pb1;
        if constexpr (NB == 4) {
            *(uint4*)&Bs[(64 + r0) * 64 + cs] = pb2;
            *(uint4*)&Bs[(96 + r0) * 64 + cs] = pb3;
        }
        __syncthreads();
        if (k0 + 64 < ks) {   // prefetch next slab; vmcnt waits land next iteration
            int k = k0 + 64;
            pa0 = *(const uint4*)(Ap + k);
            pa1 = *(const uint4*)(Ap + sA + k);
            if constexpr (NA == 4) {
                pa2 = *(const uint4*)(Ap + 2 * sA + k);
                pa3 = *(const uint4*)(Ap + 3 * sA + k);
            }
            pb0 = *(const uint4*)(Bp + k);
            pb1 = *(const uint4*)(Bp + sA + k);
            if constexpr (NB == 4) {
                pb2 = *(const uint4*)(Bp + 2 * sA + k);
                pb3 = *(const uint4*)(Bp + 3 * sA + k);
            }
        }
#pragma unroll
        for (int kk = 0; kk < 2; kk++) {
            short8 af[MI], bfr[MI];
#pragma unroll
            for (int i = 0; i < MI; i++) af[i]  = *(const short8*)&As[(wm_off + i * 16 + qr) * 64 + cswz[kk]];
#pragma unroll
            for (int j = 0; j < MI; j++) bfr[j] = *(const short8*)&Bs[(wn_off + j * 16 + qr) * 64 + cswz[kk]];
#pragma unroll
            for (int i = 0; i < MI; i++)
#pragma unroll
                for (int j = 0; j < MI; j++)
                    acc[i][j] = __builtin_amdgcn_mfma_f32_16x16x32_bf16(af[i], bfr[j], acc[i][j], 0, 0, 0);
        }
    }
    // epilogue: C/D layout col=lane&15, row=quad*4+reg
    float* outz = (EPI == 0) ? ((float*)OUT + (size_t)blockIdx.z * M * N) : (float*)OUT;
#pragma unroll
    for (int i = 0; i < MI; i++) {
#pragma unroll
        for (int j = 0; j < MI; j++) {
#pragma unroll
            for (int r = 0; r < 4; r++) {
                int row = m0 + wm_off + i * 16 + quad * 4 + r;
                int col = n0 + wn_off + j * 16 + qr;
                size_t idx = (size_t)row * N + col;
                float v = acc[i][j][r];
                if (EPI == 0)      outz[idx] = v;
                else if (EPI == 1) ((unsigned short*)OUT)[idx] = f2b(v);
                else if (EPI == 2) ((float*)OUT)[idx] = RES[idx] + v;
                else {
                    float u = v * fmaf(v * v, 0.035677408f, 0.79788456f);
                    float e = fminf(u * 2.885390082f, 80.0f);
                    float t = exp2f(e);
                    float g = v * t / (t + 1.0f);
                    ((unsigned short*)OUT)[idx] = f2b(g);
                }
            }
        }
    }
}

// ---------- 8-phase 256x256 bf16 GEMM (T3+T4: counted-vmcnt deep pipeline) ----
// C[M][N] = A[M][K] @ BT[N][K]^T, K%128==0. 512 thr = 8 waves (2Mx4N); per-wave
// C = 128x64. LDS 128KB: 2 fixed bufs (even K-tile -> buf0, odd -> buf1), each
// A[256][64]+B[256][64] bf16, column-rotate swizzle (phys blk = (log+row)&7).
// Staging: global_load_lds dwordx4, linear dest + pre-rotated source (rule 21).
// Per 2-K-tile iteration: 8 phases, each {ds_read frags | stage half-tiles |
// s_barrier | lgkmcnt(0) | 16 MFMA | s_barrier}. Stage placed in the phase
// AFTER its LDS region's last-reader barrier (WAR-safe by program order).
// Counted waits: vmcnt(4) before entering ph0/ph4 (leaves 4 loads in flight,
// never drains to 0 in the main loop). Prologue: stage tiles 0,1; vmcnt(8).
// EPI: 1 = bf16 store, 3 = gelu -> bf16
template <int EPI>
__global__ __launch_bounds__(512, 2) void k_gemm_8p(
        const unsigned short* __restrict__ A, const unsigned short* __restrict__ BT,
        void* __restrict__ OUT, int M, int N, int K) {
    __shared__ __align__(16) unsigned short As[2][256 * 64];   // 64 KB
    __shared__ __align__(16) unsigned short Bs[2][256 * 64];   // 64 KB
    int tid = threadIdx.x;
    int lane = tid & 63, wave = tid >> 6;       // 8 waves
    int quad = lane >> 4, qr = lane & 15;
    int wr = wave >> 2, wc = wave & 3;          // 2 x 4 wave grid
    int m0 = blockIdx.y * 256, n0 = blockIdx.x * 256;
    int nk = K / 64;                            // even (K=1024 -> 16)

    // staging: thread t covers row (t>>3) of each 64-row round, col-block (t&7)
    int srow = tid >> 3, sblk = tid & 7;
    int scol = 8 * ((sblk - (srow & 7)) & 7);   // pre-rotated source col (shorts)
    const unsigned short* Ag = A  + (size_t)(m0 + srow) * K + scol;
    const unsigned short* Bg = BT + (size_t)(n0 + srow) * K + scol;
    const size_t rstep = (size_t)64 * K;        // 64 rows

    int cswz[2];
#pragma unroll
    for (int kk = 0; kk < 2; kk++) cswz[kk] = 8 * (((kk * 4) + quad + (qr & 7)) & 7);

    // stage one half-tile (128 rows = 2 rounds, 2 gloads) of tile kt into buf
    auto stageA = [&](int buf, int half, int kt) {
        int k = (kt < nk ? kt : 0) * 64;
#pragma unroll
        for (int rr = 0; rr < 2; rr++) {
            int r4 = half * 2 + rr;
            gload16(Ag + (size_t)r4 * rstep + k, &As[buf][r4 * 4096 + wave * 512]);
        }
    };
    auto stageB = [&](int buf, int half, int kt) {
        int k = (kt < nk ? kt : 0) * 64;
#pragma unroll
        for (int rr = 0; rr < 2; rr++) {
            int r4 = half * 2 + rr;
            gload16(Bg + (size_t)r4 * rstep + k, &Bs[buf][r4 * 4096 + wave * 512]);
        }
    };

    f32x4 acc[8][4] = {};
    // ---- prologue: stage tiles 0 (buf0) and 1 (buf1) fully ----
    stageA(0, 0, 0); stageA(0, 1, 0); stageB(0, 0, 0); stageB(0, 1, 0);
    stageA(1, 0, 1); stageA(1, 1, 1); stageB(1, 0, 1); stageB(1, 1, 1);
    asm volatile("s_waitcnt vmcnt(8)" ::: "memory");   // tile 0 resident
    __builtin_amdgcn_s_barrier();

    short8 bf[4][2];
    for (int t = 0; t < nk; t += 2) {
#pragma unroll
        for (int ph = 0; ph < 8; ph++) {
            const int B = ph >> 2;      // buf / tile select (t+B)
            const int p = ph & 3;       // quadrant
            // ---- ds_read fragments ----
            if (p == 0) {
#pragma unroll
                for (int j = 0; j < 4; j++)
#pragma unroll
                    for (int kk = 0; kk < 2; kk++)
                        bf[j][kk] = *(const short8*)&Bs[B][(wc * 64 + j * 16 + qr) * 64 + cswz[kk]];
            }
            short8 af[2][2];
#pragma unroll
            for (int i2 = 0; i2 < 2; i2++)
#pragma unroll
                for (int kk = 0; kk < 2; kk++)
                    af[i2][kk] = *(const short8*)&As[B][(wr * 128 + (p * 2 + i2) * 16 + qr) * 64 + cswz[kk]];
            // ---- stage half-tiles (region died at previous phase's barrier) ----
            if (ph == 0)      { if (t) stageA(1, 0, t + 1); }
            else if (ph == 1) { if (t) stageA(1, 1, t + 1); stageB(0, 0, t + 2); }
            else if (ph == 2) { stageB(0, 1, t + 2); }
            else if (ph == 4) { stageA(0, 0, t + 2); }
            else if (ph == 5) { stageA(0, 1, t + 2); stageB(1, 0, t + 3); }
            else if (ph == 6) { stageB(1, 1, t + 3); }
            // ---- MFMA cluster ----
            __builtin_amdgcn_s_barrier();
            asm volatile("s_waitcnt lgkmcnt(0)" ::: "memory");
            __builtin_amdgcn_sched_barrier(0);
            __builtin_amdgcn_s_setprio(1);
#pragma unroll
            for (int i2 = 0; i2 < 2; i2++)
#pragma unroll
                for (int kk = 0; kk < 2; kk++)
#pragma unroll
                    for (int j = 0; j < 4; j++)
                        acc[p * 2 + i2][j] = __builtin_amdgcn_mfma_f32_16x16x32_bf16(
                            af[i2][kk], bf[j][kk], acc[p * 2 + i2][j], 0, 0, 0);
            __builtin_amdgcn_s_setprio(0);
            if (p == 3) asm volatile("s_waitcnt vmcnt(4)" ::: "memory");
            __builtin_amdgcn_s_barrier();
        }
    }
    asm volatile("s_waitcnt vmcnt(0)" ::: "memory");   // drain tail garbage stages

    // ---- epilogue: C/D layout col=lane&15, row=quad*4+reg ----
#pragma unroll
    for (int i = 0; i < 8; i++) {
#pragma unroll
        for (int j = 0; j < 4; j++) {
#pragma unroll
            for (int r = 0; r < 4; r++) {
                int row = m0 + wr * 128 + i * 16 + quad * 4 + r;
                int col = n0 + wc * 64 + j * 16 + qr;
                size_t idx = (size_t)row * N + col;
                float v = acc[i][j][r];
                if (EPI == 1) ((unsigned short*)OUT)[idx] = f2b(v);
                else {
                    float u = v * fmaf(v * v, 0.035677408f, 0.79788456f);
                    float e = fminf(u * 2.885390082f, 80.0f);
                    float tt = exp2f(e);
                    float g = v * tt / (tt + 1.0f);
                    ((unsigned short*)OUT)[idx] = f2b(g);
                }
            }
        }
    }
}

// ---------- MFMA causal flash attention, K-chunk=128, static-max softmax ------
// R0 baseline kernel, byte-identical (best measured: 98.2us).
__global__ __launch_bounds__(256) void k_attn(
        const unsigned short* __restrict__ qkv, unsigned short* __restrict__ out) {
    __shared__ unsigned short Ks[128][72];      // K rows (Q staged here first)
    __shared__ unsigned short Vt[64][136];      // [dim][key 0..127]
    __shared__ unsigned short Ps[4][16][136];   // per wave [q][key 0..127] (wave-private)

    const float C1 = 0.18033688f;   // 0.125 * log2(e)
    const float C2 = 5.77078016f;   // 4.0   * log2(e)  (static max m=4)

    int l = blockIdx.x;                // 0..1023; big qb dispatched first
    int h = l & 15;
    int qb = 63 - (l >> 4);
    int q0 = qb * 64;

    int tid = threadIdx.x;
    int wave = tid >> 6, lane = tid & 63;
    int lane16 = lane & 15, quad = lane >> 4;

    // ---- stage Q through Ks rows 0..63, read loop-invariant A-frags ----
    {
        int srow = tid >> 2, sc0 = (tid & 3) * 16;
        size_t base = (size_t)(q0 + srow) * 3072 + h * 64 + sc0;
        *(uint4*)&Ks[srow][sc0]     = *(const uint4*)&qkv[base];
        *(uint4*)&Ks[srow][sc0 + 8] = *(const uint4*)&qkv[base + 8];
    }
    __syncthreads();
    short8 aq0 = *(const short8*)&Ks[wave * 16 + lane16][quad * 8];
    short8 aq1 = *(const short8*)&Ks[wave * 16 + lane16][32 + quad * 8];

    f32x4 Oacc[4] = {};                // lane holds O[q=quad*4+r][d=dt*16+lane16]
    float l_part[4] = {0.f, 0.f, 0.f, 0.f};

    int srow = tid >> 1, sc0 = (tid & 1) * 32;   // K staging coords
    int vk = (lane & 31) * 2;                    // V staging: even local key
    int d0 = wave * 16 + (lane >> 5) * 8;

    // prefetch registers (chunk kc): K 4x uint4, V 4x uint4
    uint4 pk0, pk1, pk2, pk3, pv0, pv1, pv2, pv3;
    {   // prefetch chunk 0
        size_t base = (size_t)srow * 3072 + 1024 + h * 64 + sc0;
        pk0 = *(const uint4*)&qkv[base];
        pk1 = *(const uint4*)&qkv[base + 8];
        pk2 = *(const uint4*)&qkv[base + 16];
        pk3 = *(const uint4*)&qkv[base + 24];
        size_t vb0 = (size_t)vk * 3072 + 2048 + h * 64 + d0;
        pv0 = *(const uint4*)&qkv[vb0];
        pv1 = *(const uint4*)&qkv[vb0 + 3072];
        size_t vb1 = (size_t)(64 + vk) * 3072 + 2048 + h * 64 + d0;
        pv2 = *(const uint4*)&qkv[vb1];
        pv3 = *(const uint4*)&qkv[vb1 + 3072];
    }

    for (int kc = 0; kc <= qb; kc += 2) {      // 128 keys per iteration
        __syncthreads();   // prev-iter LDS reads done (covers Q-frag reads at kc=0)
        {   // write prefetched K chunk to LDS
            *(uint4*)&Ks[srow][sc0]      = pk0;
            *(uint4*)&Ks[srow][sc0 + 8]  = pk1;
            *(uint4*)&Ks[srow][sc0 + 16] = pk2;
            *(uint4*)&Ks[srow][sc0 + 24] = pk3;
        }
        {   // write prefetched V chunk TRANSPOSED, key-pairs packed as b32
            const unsigned short* pe0 = (const unsigned short*)&pv0;
            const unsigned short* po0 = (const unsigned short*)&pv1;
            const unsigned short* pe1 = (const unsigned short*)&pv2;
            const unsigned short* po1 = (const unsigned short*)&pv3;
#pragma unroll
            for (int j = 0; j < 8; j++) {
                *(uint32_t*)&Vt[d0 + j][vk]      = (uint32_t)pe0[j] | ((uint32_t)po0[j] << 16);
                *(uint32_t*)&Vt[d0 + j][64 + vk] = (uint32_t)pe1[j] | ((uint32_t)po1[j] << 16);
            }
        }
        __syncthreads();

        if (kc + 2 <= qb) {   // issue next chunk's loads; overlap with compute below
            size_t base = (size_t)((kc + 2) * 64 + srow) * 3072 + 1024 + h * 64 + sc0;
            pk0 = *(const uint4*)&qkv[base];
            pk1 = *(const uint4*)&qkv[base + 8];
            pk2 = *(const uint4*)&qkv[base + 16];
            pk3 = *(const uint4*)&qkv[base + 24];
            size_t vb0 = (size_t)((kc + 2) * 64 + vk) * 3072 + 2048 + h * 64 + d0;
            pv0 = *(const uint4*)&qkv[vb0];
            pv1 = *(const uint4*)&qkv[vb0 + 3072];
            size_t vb1 = (size_t)((kc + 3) * 64 + vk) * 3072 + 2048 + h * 64 + d0;
            pv2 = *(const uint4*)&qkv[vb1];
            pv3 = *(const uint4*)&qkv[vb1 + 3072];
        }

        // ---- S = Q K^T  (16q x 128k per wave) ----
        f32x4 sacc[8] = {};
#pragma unroll
        for (int kt = 0; kt < 8; kt++) {
            short8 bk0 = *(const short8*)&Ks[kt * 16 + lane16][quad * 8];
            short8 bk1 = *(const short8*)&Ks[kt * 16 + lane16][32 + quad * 8];
            sacc[kt] = __builtin_amdgcn_mfma_f32_16x16x32_bf16(aq0, bk0, sacc[kt], 0, 0, 0);
            sacc[kt] = __builtin_amdgcn_mfma_f32_16x16x32_bf16(aq1, bk1, sacc[kt], 0, 0, 0);
        }

        // ---- static-max softmax: p = 2^(s*C1 - C2); mask only on last chunk ----
        bool domask = (kc + 2 > qb);   // wave-uniform
#pragma unroll
        for (int r = 0; r < 4; r++) {
            int qrow = q0 + wave * 16 + quad * 4 + r;
#pragma unroll
            for (int kt = 0; kt < 8; kt++) {
                float s = sacc[kt][r];
                if (domask) {
                    int key = kc * 64 + kt * 16 + lane16;
                    s = (key <= qrow) ? s : -__builtin_inff();
                }
                float p = exp2f(fmaf(s, C1, -C2));   // masked -> 0
                l_part[r] += p;
                Ps[wave][quad * 4 + r][kt * 16 + lane16] =
                    (unsigned short)(__float_as_uint(p) >> 16);   // truncated bf16
            }
        }
        // no barrier: Ps is wave-private; in-wave RAW ordered by lgkmcnt

        // ---- O += P V  (A=P rows, B=V^T rows, both key-contiguous) ----
#pragma unroll
        for (int s = 0; s < 4; s++) {
            short8 ap = *(const short8*)&Ps[wave][lane16][s * 32 + quad * 8];
#pragma unroll
            for (int dt = 0; dt < 4; dt++) {
                short8 bv = *(const short8*)&Vt[dt * 16 + lane16][s * 32 + quad * 8];
                Oacc[dt] = __builtin_amdgcn_mfma_f32_16x16x32_bf16(ap, bv, Oacc[dt], 0, 0, 0);
            }
        }
    }

    // deferred l reduction (sum over lane16 key-group) + output
    float invl[4];
#pragma unroll
    for (int r = 0; r < 4; r++) {
        float lf = l_part[r];
        lf += __shfl_xor(lf, 1);
        lf += __shfl_xor(lf, 2);
        lf += __shfl_xor(lf, 4);
        lf += __shfl_xor(lf, 8);
        invl[r] = 1.0f / lf;
    }
#pragma unroll
    for (int dt = 0; dt < 4; dt++) {
#pragma unroll
        for (int r = 0; r < 4; r++) {
            int qrow = q0 + wave * 16 + quad * 4 + r;
            out[(size_t)qrow * 1024 + h * 64 + dt * 16 + lane16] = f2b(Oacc[dt][r] * invl[r]);
        }
    }
}

// ---------- launch ----------
extern "C" void kernel_launch(void* const* d_in, const int* in_sizes, int n_in,
                              void* d_out, int out_size, void* d_ws, size_t ws_size,
                              hipStream_t stream) {
    const float* x      = (const float*)d_in[0];
    const float* w_qkv  = (const float*)d_in[1];
    const float* w_attn = (const float*)d_in[2];
    const float* w_fc   = (const float*)d_in[3];
    const float* w_mlp  = (const float*)d_in[4];
    const float* ln1w   = (const float*)d_in[5];
    const float* ln2w   = (const float*)d_in[6];

    char* ws = (char*)d_ws;   // total 116 MB (region reuse for split-K partials)
    unsigned short* h      = (unsigned short*)(ws + 0);          //  8 MB
    unsigned short* wqkvT  = (unsigned short*)(ws + 8388608);    //  6 MB
    unsigned short* wattnT = (unsigned short*)(ws + 14680064);   //  2 MB
    unsigned short* wfcT   = (unsigned short*)(ws + 16777216);   //  8 MB
    unsigned short* wmlpT  = (unsigned short*)(ws + 25165824);   //  8 MB
    unsigned short* qkv    = (unsigned short*)(ws + 33554432);   // 24 MB
    unsigned short* attno  = (unsigned short*)(ws + 58720256);   //  8 MB
    float*          x2     = (float*)(ws + 67108864);            // 16 MB
    unsigned short* fcact  = (unsigned short*)(ws + 83886080);   // 32 MB
    // split-K partials (32 MB each, region-reuse of dead buffers):
    float* pA = (float*)(ws + 83886080);   // attn_proj partials: fcact region (dead until fc)
    float* pM = (float*)(ws + 33554432);   // mlp partials: qkv+attno region (dead after attn_proj)
    float* outF = (float*)d_out;

    k_transpose_all<<<12288, dim3(32, 8), 0, stream>>>(
        w_qkv, w_attn, w_fc, w_mlp, wqkvT, wattnT, wfcT, wmlpT);

    k_layernorm<<<4096, 256, 0, stream>>>(x, ln1w, h);
    k_gemm_8p<1><<<dim3(12, 16), 512, 0, stream>>>(h, wqkvT, qkv, 4096, 3072, 1024);
    k_attn<<<1024, 256, 0, stream>>>(qkv, attno);
    // attn_proj: split-K=2, fp32 partials -> pA; fused reduce+LN adds residual x
    k_gemm_bt<0, 128, 128, 3><<<dim3(8, 32, 2), 256, 0, stream>>>(attno, wattnT, nullptr, pA, 4096, 1024, 1024);
    k_reduce_ln<<<4096, 256, 0, stream>>>(x, pA, pA + 4194304, ln2w, x2, h);
    k_gemm_8p<3><<<dim3(16, 16), 512, 0, stream>>>(h, wfcT, fcact, 4096, 4096, 1024);
    // mlp_proj: split-K=2, fp32 partials -> pM; reduce adds residual x2
    k_gemm_bt<0, 128, 128, 3><<<dim3(8, 32, 2), 256, 0, stream>>>(fcact, wmlpT, nullptr, pM, 4096, 1024, 4096);
    k_reduce<<<4096, 256, 0, stream>>>(x2, pM, pM + 4194304, outF, 1048576);
}